// Round 4
// baseline (345.737 us; speedup 1.0000x reference)
//
#include <hip/hip_runtime.h>

// Retrace loss: per-row backward affine recurrence y[s] = A[s]*y[s-1] + B[s].
//
// R4 structure: ONE WAVE PER ROW, persistent loop over 16 chunks of 256
// elements (lane owns one float4 per array per chunk). Register double-buffer
// keeps 6 KB of loads in flight per wave at ALL times -> 16 waves/CU x 6 KB =
// 96 KB/CU outstanding, sustaining ~6 TB/s delivered even at ~3000-cycle
// loaded latency. (R1-R3 were all one-shot waves: one load volley, one wait,
// then a load-free tail -> duty-cycle-limited at ~3.1 TB/s delivered, which
// is why three different one-shot structures all measured 122-132 us.)
// No barriers, no LDS arrays; recurrence crosses chunks via a wave-uniform
// running state (2 lane-63 broadcasts/chunk) and the u=t+1 shifted window
// crosses chunks via 4 lane-63 broadcasts of the previous chunk's .x values.

#define NROWS 4096
#define TLEN  4096
#define CHUNK 256                 // 64 lanes x 4 elements
#define NCHUNK (TLEN / CHUNK)     // 16
#define BLOCK 256
#define WPB   (BLOCK / 64)        // waves per block = 4

__global__ __launch_bounds__(BLOCK) void retrace_main(
    const float* __restrict__ Q,
    const float* __restrict__ eQ,
    const float* __restrict__ tQ,
    const float* __restrict__ rw,
    const float* __restrict__ tpp,
    const float* __restrict__ bpp,
    double* __restrict__ partials)
{
    constexpr float G = 0.99f;
    const int lane = threadIdx.x & 63;
    const int row  = blockIdx.x * WPB + (threadIdx.x >> 6);   // one wave per row
    const long long base = (long long)row * TLEN;

    // Virtual position: chunk c, lane l covers backward indices
    // s in [4*(64c+l), 4*(64c+l)+4); element window ua = 4092 - 256c - 4l.
    const int ua0 = (TLEN - 4) - 4 * lane;     // chunk-0 window start

    // ---- chunk 0 loads (current buffer) ----
    float4 cR  = *(const float4*)(rw  + base + ua0);
    float4 cT  = *(const float4*)(tpp + base + ua0);
    float4 cP  = *(const float4*)(bpp + base + ua0);
    float4 cQt = *(const float4*)(tQ  + base + ua0);
    float4 cE  = *(const float4*)(eQ  + base + ua0);
    float4 cQm = *(const float4*)(Q   + base + ua0);

    float y_state = 0.0f;          // wave-uniform running Q_ret state
    float acc     = 0.0f;          // per-lane squared-error accumulator
    float pTx = 0.f, pPx = 0.f, pQtx = 0.f, pEx = 0.f;  // prev chunk .x saves

    #pragma unroll 1
    for (int c = 0; c < NCHUNK; ++c) {
        // ---- issue NEXT chunk's loads before touching current data ----
        float4 nR, nT, nP, nQt, nE, nQm;
        if (c + 1 < NCHUNK) {
            const int uan = ua0 - (c + 1) * CHUNK;
            nR  = *(const float4*)(rw  + base + uan);
            nT  = *(const float4*)(tpp + base + uan);
            nP  = *(const float4*)(bpp + base + uan);
            nQt = *(const float4*)(tQ  + base + uan);
            nE  = *(const float4*)(eQ  + base + uan);
            nQm = *(const float4*)(Q   + base + uan);
        }

        // ---- shifted-window (u = ua+4) element = virtual-neighbor's .x ----
        float t4v = __shfl_up(cT.x,  1, 64);
        float p4v = __shfl_up(cP.x,  1, 64);
        float q4v = __shfl_up(cQt.x, 1, 64);
        float e4v = __shfl_up(cE.x,  1, 64);
        // lane 0's neighbor is lane 63 of the PREVIOUS chunk
        const float bT = __shfl(pTx,  63, 64);
        const float bP = __shfl(pPx,  63, 64);
        const float bQ = __shfl(pQtx, 63, 64);
        const float bE = __shfl(pEx,  63, 64);
        if (lane == 0 && c > 0) { t4v = bT; p4v = bP; q4v = bQ; e4v = bE; }

        const float rv[4] = {cR.x,  cR.y,  cR.z,  cR.w};
        const float tv[4] = {cT.x,  cT.y,  cT.z,  cT.w};
        const float pv[4] = {cP.x,  cP.y,  cP.z,  cP.w};
        const float qv[4] = {cQt.x, cQt.y, cQt.z, cQt.w};
        const float ev[4] = {cE.x,  cE.y,  cE.z,  cE.w};
        const float qm[4] = {cQm.x, cQm.y, cQm.z, cQm.w};

        // ---- build 4 affine maps (idx = m-1): A = G*cr(u),
        //      B = 100*r[u-1] + G*(eq[u] - cr*tq[u]), u = ua+m ----
        float Aa[4], Bb[4];
        #pragma unroll
        for (int m = 1; m <= 3; ++m) {
            const float cr = __expf(fminf(tv[m] - pv[m], 0.0f));
            const float gc = G * cr;
            Aa[m - 1] = gc;
            Bb[m - 1] = fmaf(100.0f, rv[m - 1], fmaf(-gc, qv[m], G * ev[m]));
        }
        if (c == 0 && lane == 0) {
            // s = 0 anchor: y = tQ[T-1] exactly (A = 0 kills prior state).
            Aa[3] = 0.0f;
            Bb[3] = qv[3];                 // tQ[base + TLEN - 1]
        } else {
            const float cr = __expf(fminf(t4v - p4v, 0.0f));
            const float gc = G * cr;
            Aa[3] = gc;
            Bb[3] = fmaf(100.0f, rv[3], fmaf(-gc, q4v, G * e4v));
        }

        // ---- local sequential composite (maps applied idx = 3 down to 0) ----
        float Ac = 1.0f, Bc = 0.0f;
        #pragma unroll
        for (int k = 0; k < 4; ++k) {
            const int idx = 3 - k;
            Bc = fmaf(Aa[idx], Bc, Bb[idx]);
            Ac = Aa[idx] * Ac;
        }

        // ---- wave inclusive scan of affine maps ----
        float Ai = Ac, Bi = Bc;
        #pragma unroll
        for (int off = 1; off < 64; off <<= 1) {
            const float Ap = __shfl_up(Ai, off, 64);
            const float Bp = __shfl_up(Bi, off, 64);
            if (lane >= off) {
                Bi = fmaf(Ai, Bp, Bi);
                Ai = Ai * Ap;
            }
        }

        // ---- entry state for this lane, apply maps, accumulate loss ----
        float Ae = __shfl_up(Ai, 1, 64);
        float Be = __shfl_up(Bi, 1, 64);
        if (lane == 0) { Ae = 1.0f; Be = 0.0f; }
        float y = fmaf(Ae, y_state, Be);

        #pragma unroll
        for (int k = 0; k < 4; ++k) {
            const int idx = 3 - k;
            y = fmaf(Aa[idx], y, Bb[idx]);     // y = Q_ret[t], t = ua + idx
            const float d = qm[idx] - y;
            acc = fmaf(d, d, acc);
        }

        // ---- advance wave-uniform state: composite of whole chunk ----
        const float A63 = __shfl(Ai, 63, 64);
        const float B63 = __shfl(Bi, 63, 64);
        y_state = fmaf(A63, y_state, B63);

        // ---- rotate buffers ----
        pTx = cT.x; pPx = cP.x; pQtx = cQt.x; pEx = cE.x;
        cR = nR; cT = nT; cP = nP; cQt = nQt; cE = nE; cQm = nQm;
    }

    // ---- wave reduction of the loss; one write per row ----
    #pragma unroll
    for (int off = 32; off > 0; off >>= 1)
        acc += __shfl_down(acc, off, 64);
    if (lane == 0)
        partials[row] = (double)acc;   // all 4096 slots written -> poison-safe
}

__global__ __launch_bounds__(256) void retrace_finalize(
    const double* __restrict__ partials, float* __restrict__ out)
{
    __shared__ double sRed[4];
    double s = 0.0;
    for (int i = threadIdx.x; i < NROWS; i += 256) s += partials[i];
    #pragma unroll
    for (int off = 32; off > 0; off >>= 1)
        s += __shfl_down(s, off, 64);
    if ((threadIdx.x & 63) == 0) sRed[threadIdx.x >> 6] = s;
    __syncthreads();
    if (threadIdx.x == 0) {
        const double tot = sRed[0] + sRed[1] + sRed[2] + sRed[3];
        out[0] = (float)(tot / ((double)NROWS * (double)TLEN));
    }
}

extern "C" void kernel_launch(void* const* d_in, const int* in_sizes, int n_in,
                              void* d_out, int out_size, void* d_ws, size_t ws_size,
                              hipStream_t stream)
{
    // setup_inputs order: Q, expected_target_Q, target_Q, rewards,
    //                     target_policy_probs, behaviour_policy_probs
    const float* Q   = (const float*)d_in[0];
    const float* eQ  = (const float*)d_in[1];
    const float* tQ  = (const float*)d_in[2];
    const float* rw  = (const float*)d_in[3];
    const float* tpp = (const float*)d_in[4];
    const float* bpp = (const float*)d_in[5];
    double* partials = (double*)d_ws;       // 4096 doubles = 32 KB scratch

    retrace_main<<<NROWS / WPB, BLOCK, 0, stream>>>(Q, eQ, tQ, rw, tpp, bpp, partials);
    retrace_finalize<<<1, 256, 0, stream>>>(partials, (float*)d_out);
}